// Round 5
// baseline (325.777 us; speedup 1.0000x reference)
//
#include <hip/hip_runtime.h>

typedef __attribute__((ext_vector_type(4))) float floatx4;
typedef __attribute__((ext_vector_type(8))) short short8;
typedef __attribute__((ext_vector_type(8))) unsigned short ushort8v;

__device__ __forceinline__ unsigned short f2bf(float f) {
  // round-to-nearest-even fp32 -> bf16 (inputs are finite)
  unsigned int u = __builtin_bit_cast(unsigned int, f);
  u += 0x7FFFu + ((u >> 16) & 1u);
  return (unsigned short)(u >> 16);
}

#define KTOT 784   // true K (28*28)
#define KP2  832   // padded K (13 * 64); Bt zeros in [784,832)
#define N1   128   // hidden width
#define BM   128   // rows per block
#define LDH  132   // LDS stride (ushorts) for h / w2t: 128 + 4 pad

// async global->LDS DMA, 16 B per lane; LDS dst = uniform base + lane*16
typedef const __attribute__((address_space(1))) unsigned int* gas_ptr;
typedef __attribute__((address_space(3))) unsigned int* las_ptr;
__device__ __forceinline__ void dma16(const float* g, float* l) {
  __builtin_amdgcn_global_load_lds((gas_ptr)g, (las_ptr)l, 16, 0, 0);
}

// ---------------------------------------------------------------------------
// Prep: W1eff[q][n] = sum_{di,dj} conv_w[di,dj] * w1[(r-di)*26 + (c-dj)][n]
// stored TRANSPOSED as Bt[n][k] bf16, k padded to 832 with zeros.
// ---------------------------------------------------------------------------
__global__ void prep_w1eff(const float* __restrict__ conv_w,
                           const float* __restrict__ w1,
                           unsigned short* __restrict__ Bt) {
  const int n = blockIdx.x;  // 0..127
  float cw[9];
#pragma unroll
  for (int i = 0; i < 9; ++i) cw[i] = conv_w[i];
  for (int q = threadIdx.x; q < KP2; q += blockDim.x) {
    float acc = 0.f;
    if (q < KTOT) {
      const int r = q / 28, c = q % 28;
#pragma unroll
      for (int di = 0; di < 3; ++di) {
        const int i2 = r - di;
        if (i2 < 0 || i2 >= 26) continue;
#pragma unroll
        for (int dj = 0; dj < 3; ++dj) {
          const int j2 = c - dj;
          if (j2 < 0 || j2 >= 26) continue;
          acc += cw[di * 3 + dj] * w1[(i2 * 26 + j2) * N1 + n];
        }
      }
    }
    Bt[n * KP2 + q] = f2bf(acc);
  }
}

// ---------------------------------------------------------------------------
// Fused: out = relu(x @ W1eff + b1) @ w2 + b2
// m97-verified structure: per K-step (BK=64): __syncthreads; DMA-issue
// (global_load_lds x4/wave, chunk-xor swizzle); __syncthreads (full drain);
// compute from LDS. No inline asm, no hand waitcnts — compiler-friendly.
// 512 thr (8 waves: 4m x 2n), single 32KB A buffer, B direct L2->reg.
// ---------------------------------------------------------------------------
__global__ __launch_bounds__(512, 4)
void fused_mlp(const float* __restrict__ x,
               const unsigned short* __restrict__ Bt,
               const float* __restrict__ b1,
               const float* __restrict__ w2,
               const float* __restrict__ b2,
               float* __restrict__ out) {
  __shared__ __align__(16) unsigned char smem[38592];
  float* sAf = (float*)smem;                   // [2 subtiles][128 rows][32 fp32] swizzled
  unsigned short* sH = (unsigned short*)smem;  // overlay: [128][LDH]
  unsigned short* sW2t = (unsigned short*)(smem + 33792);  // [16][LDH]
  float* sB1 = (float*)(smem + 38016);
  float* sB2 = (float*)(smem + 38528);

  const int tid  = threadIdx.x;
  const int wave = tid >> 6;   // 0..7
  const int lane = tid & 63;
  const int wm = wave >> 1;    // 0..3 -> 32-row slice
  const int wn = wave & 1;     // 0..1 -> 64-col slice
  const int lr = lane & 15;
  const int lq = lane >> 4;

  const long row_base = (long)blockIdx.x * BM;
  const float* xblk = x + row_base * KTOT;

  // preload w2 (transposed bf16, padded to 16 cols), b1, b2
  for (int i = tid; i < 16 * N1; i += 512) {
    const int n = i >> 7, k = i & 127;
    sW2t[n * LDH + k] = (n < 10) ? f2bf(w2[k * 10 + n]) : (unsigned short)0;
  }
  if (tid < N1) sB1[tid] = b1[tid];
  if (tid >= N1 && tid < N1 + 10) sB2[tid - N1] = b2[tid - N1];

  // --- DMA lane mapping (R4-proven swizzle, per 32-K subtile) ---
  // instr covers 8 rows; lane: rsub = lane>>3 (row in group), slot = lane&7,
  // slot holds global chunk cg = slot ^ (row&6).
  const int rsub = lane >> 3;
  const int cg   = (lane & 7) ^ (rsub & 6);
  const int ceff = (cg < 4) ? cg : cg - 4;   // tail clamp target chunk
  const int r0 = wave * 16 + rsub;           // this wave's row-group 0
  const int r1 = wave * 16 + 8 + rsub;       // row-group 1
  const float* g0 = xblk + (long)r0 * KTOT + cg * 4;
  const float* g1 = xblk + (long)r1 * KTOT + cg * 4;
  float* l00 = sAf + (wave * 2) * 256;            // subtile0, group0
  float* l01 = sAf + (wave * 2 + 1) * 256;        // subtile0, group1
  float* l10 = sAf + 4096 + (wave * 2) * 256;     // subtile1, group0
  float* l11 = sAf + 4096 + (wave * 2 + 1) * 256; // subtile1, group1

  // B fragment pointers: Bt[n][k], n = wn*64 + in*16 + lr, k = lq*8 (+step)
  const unsigned short* bptr[4];
#pragma unroll
  for (int in = 0; in < 4; ++in)
    bptr[in] = Bt + (long)(wn * 64 + in * 16 + lr) * KP2 + lq * 8;

  floatx4 acc[2][4] = {};

  auto compute_step = [&](int kt) {
#pragma unroll
    for (int s = 0; s < 2; ++s) {
      ushort8v rB[4];
#pragma unroll
      for (int in = 0; in < 4; ++in)
        rB[in] = *(const ushort8v*)(bptr[in] + kt * 64 + s * 32);
      short8 af[2];
#pragma unroll
      for (int im = 0; im < 2; ++im) {
        const int r = wm * 32 + im * 16 + lr;
        const int s0 = (2 * lq) ^ (r & 6);
        const floatx4* p = (const floatx4*)(sAf + s * 4096 + r * 32 + s0 * 4);
        const floatx4 q0 = p[0], q1 = p[1];
        ushort8v u;
#pragma unroll
        for (int j = 0; j < 4; ++j) { u[j] = f2bf(q0[j]); u[4 + j] = f2bf(q1[j]); }
        af[im] = __builtin_bit_cast(short8, u);
      }
#pragma unroll
      for (int im = 0; im < 2; ++im)
#pragma unroll
        for (int in = 0; in < 4; ++in)
          acc[im][in] = __builtin_amdgcn_mfma_f32_16x16x32_bf16(
              af[im], __builtin_bit_cast(short8, rB[in]), acc[im][in], 0, 0, 0);
    }
  };

  // K-loop: 12 full steps of 64
  for (int kt = 0; kt < 12; ++kt) {
    const int ko = kt * 64;
    __syncthreads();                 // prior readers of sAf done
    dma16(g0 + ko,      l00);        // subtile0: k = ko + cg*4
    dma16(g1 + ko,      l01);
    dma16(g0 + ko + 32, l10);        // subtile1: k = ko+32 + cg*4
    dma16(g1 + ko + 32, l11);
    __syncthreads();                 // drain: LDS tile ready
    compute_step(kt);
  }
  // tail step kt=12 covers k = 768..832; valid x only up to 783.
  // Clamped addr gives correct x for k<784 (cg<4 in subtile0) and
  // don't-care (Bt==0) elsewhere.
  {
    const float* t0 = xblk + (long)r0 * KTOT + 768 + ceff * 4;
    const float* t1 = xblk + (long)r1 * KTOT + 768 + ceff * 4;
    __syncthreads();
    dma16(t0, l00);
    dma16(t1, l01);
    dma16(t0, l10);
    dma16(t1, l11);
    __syncthreads();
    compute_step(12);
  }

  __syncthreads();  // all frag reads of sAf retired before sH overlay

  // h = relu(acc + b1) -> bf16 sH[row][col]; C/D: col=lane&15, row=lq*4+reg
#pragma unroll
  for (int im = 0; im < 2; ++im) {
#pragma unroll
    for (int in = 0; in < 4; ++in) {
      const int col = wn * 64 + in * 16 + lr;
      const float bb = sB1[col];
#pragma unroll
      for (int r = 0; r < 4; ++r) {
        const int row = wm * 32 + im * 16 + lq * 4 + r;
        const float v = acc[im][in][r] + bb;
        sH[row * LDH + col] = f2bf(v > 0.f ? v : 0.f);
      }
    }
  }
  __syncthreads();

  // GEMM2: out = h @ w2 + b2. Wave handles rows [wave*16, wave*16+16).
  floatx4 o = {0.f, 0.f, 0.f, 0.f};
  const int m0 = wave * 16;
#pragma unroll
  for (int kc = 0; kc < 4; ++kc) {
    const int kof = kc * 32 + lq * 8;
    const short8 wv = *(const short8*)&sW2t[lr * LDH + kof];
    const short8 a0 = *(const short8*)&sH[(m0 + lr) * LDH + kof];
    o = __builtin_amdgcn_mfma_f32_16x16x32_bf16(a0, wv, o, 0, 0, 0);
  }
  if (lr < 10) {
    const float bb = sB2[lr];
#pragma unroll
    for (int r = 0; r < 4; ++r) {
      const long row = row_base + m0 + lq * 4 + r;
      out[row * 10 + lr] = o[r] + bb;
    }
  }
}

extern "C" void kernel_launch(void* const* d_in, const int* in_sizes, int n_in,
                              void* d_out, int out_size, void* d_ws, size_t ws_size,
                              hipStream_t stream) {
  const float* x      = (const float*)d_in[0];  // 65536 x 784
  const float* conv_w = (const float*)d_in[1];  // 3 x 3
  const float* w1     = (const float*)d_in[2];  // 676 x 128
  const float* b1     = (const float*)d_in[3];  // 128
  const float* w2     = (const float*)d_in[4];  // 128 x 10
  const float* b2     = (const float*)d_in[5];  // 10
  float* out = (float*)d_out;                   // 65536 x 10

  unsigned short* Bt = (unsigned short*)d_ws;   // 128 x 832 bf16 = 212992 B

  prep_w1eff<<<128, 256, 0, stream>>>(conv_w, w1, Bt);
  fused_mlp<<<65536 / BM, 512, 0, stream>>>(x, Bt, b1, w2, b2, out);
}